// Round 11
// baseline (485.182 us; speedup 1.0000x reference)
//
#include <hip/hip_runtime.h>
#include <math.h>

namespace {

constexpr int kIn  = 128;
constexpr int kH1  = 512;
constexpr int kH2  = 300;
constexpr int kH2p = 304;   // padded to 16B granule
constexpr int kW2R = 384;   // W2T padded rows (3 x 128 col-tiles)
constexpr int kOut = 10;
constexpr float kEps = 1e-5f;

typedef __attribute__((ext_vector_type(8))) short bf16x8;
typedef __attribute__((ext_vector_type(4))) float f32x4;

__device__ __forceinline__ void atomAddF(float* p, float v) { unsafeAtomicAdd(p, v); }

__device__ __forceinline__ unsigned short f2bf(float f) {  // RNE f32->bf16
  unsigned u = __builtin_bit_cast(unsigned, f);
  unsigned r = u + 0x7fffu + ((u >> 16) & 1u);
  return (unsigned short)(r >> 16);
}
__device__ __forceinline__ float bf2f(unsigned short h) {
  return __builtin_bit_cast(float, (unsigned)h << 16);
}
__device__ __forceinline__ float blo(unsigned u) { return __builtin_bit_cast(float, u << 16); }
__device__ __forceinline__ float bhi(unsigned u) { return __builtin_bit_cast(float, u & 0xffff0000u); }
__device__ __forceinline__ unsigned pk2(float a, float b) {
  return (unsigned)f2bf(a) | ((unsigned)f2bf(b) << 16);
}

// async global(16B) -> LDS DMA; dest = wave-uniform base + lane*16
__device__ __forceinline__ void gload16(const unsigned short* g, unsigned short* l) {
  __builtin_amdgcn_global_load_lds(
      (const __attribute__((address_space(1))) unsigned int*)g,
      (__attribute__((address_space(3))) unsigned int*)l, 16, 0, 0);
}

__device__ __forceinline__ void fma8(const uint4& q, float w, float* acc) {
  acc[0] = fmaf(blo(q.x), w, acc[0]);
  acc[1] = fmaf(bhi(q.x), w, acc[1]);
  acc[2] = fmaf(blo(q.y), w, acc[2]);
  acc[3] = fmaf(bhi(q.y), w, acc[3]);
  acc[4] = fmaf(blo(q.z), w, acc[4]);
  acc[5] = fmaf(bhi(q.z), w, acc[5]);
  acc[6] = fmaf(blo(q.w), w, acc[6]);
  acc[7] = fmaf(bhi(q.w), w, acc[7]);
}

// ---------------- merged prep + degree/count ----------------
// Blocks [0, edgeBlocks): edge atomics (deg +w, cnt +1) -- latency-bound.
// Blocks [edgeBlocks, ..): conversions (st zero, W1T, W2T, xbf) -- BW-bound.
// deg/cnt pre-zeroed by hipMemsetAsync; self-loop folded into rsqrt(deg+1) later.
__global__ void k_prep_deg(const float* __restrict__ x, unsigned short* __restrict__ xbf,
                           float* __restrict__ st,
                           const float* __restrict__ W1, unsigned short* __restrict__ W1T,
                           const float* __restrict__ W2, unsigned short* __restrict__ W2T,
                           float* __restrict__ deg, int* __restrict__ cnt,
                           const int* __restrict__ ei, const float* __restrict__ ew,
                           int n, int nE, int edgeBlocks) {
  if ((int)blockIdx.x < edgeBlocks) {
    int i = blockIdx.x * blockDim.x + threadIdx.x;
    if (i < nE) {
      int c = ei[nE + i];
      atomAddF(&deg[c], ew[i]);
      atomicAdd(&cnt[c], 1);
    }
    return;
  }
  int i = (blockIdx.x - edgeBlocks) * blockDim.x + threadIdx.x;
  if (i < 4096) st[i] = 0.f;
  if (i < kIn * kH1) {  // W1T[512][128]
    int nn = i / kIn, k = i - nn * kIn;
    W1T[i] = f2bf(W1[(size_t)k * kH1 + nn]);
  }
  if (i < kW2R * kH1) {  // W2T[384][512], rows >=300 zero
    int nn = i / kH1, k = i - nn * kH1;
    W2T[i] = (nn < kH2) ? f2bf(W2[(size_t)k * kH2 + nn]) : (unsigned short)0;
  }
  if (i < n * 16) {  // xbf row-major [n][128]
    int node = i >> 4, g = i & 15;
    const float4* xp = reinterpret_cast<const float4*>(x + (size_t)node * kIn + g * 8);
    float4 v0 = xp[0], v1 = xp[1];
    uint4 o;
    o.x = pk2(v0.x, v0.y); o.y = pk2(v0.z, v0.w);
    o.z = pk2(v1.x, v1.y); o.w = pk2(v1.z, v1.w);
    reinterpret_cast<uint4*>(xbf)[i] = o;
  }
}

// ---------------- 2-phase scan: local scan (+ fused dis=rsqrt(deg+1)), block sums ----------------
__global__ void k_scan_a(int* __restrict__ cnt, int* __restrict__ bsum,
                         float* __restrict__ deg, int n) {
  __shared__ int ws[4];
  int i = blockIdx.x * 256 + threadIdx.x;
  int lane = threadIdx.x & 63, wid = threadIdx.x >> 6;
  if (i < n) deg[i] = rsqrtf(deg[i] + 1.0f);  // self-loop weight 1 folded here
  int v = (i < n) ? cnt[i] : 0;
  int s = v;
#pragma unroll
  for (int off = 1; off < 64; off <<= 1) {
    int t = __shfl_up(s, off);
    if (lane >= off) s += t;
  }
  if (lane == 63) ws[wid] = s;
  __syncthreads();
  int add = 0;
  if (wid > 0) add += ws[0];
  if (wid > 1) add += ws[1];
  if (wid > 2) add += ws[2];
  if (i < n) cnt[i] = s - v + add;  // block-local exclusive scan
  if (threadIdx.x == 255) bsum[blockIdx.x] = add + s;
}

__global__ void k_scan_b(int* __restrict__ bsum, int nb) {  // nb <= 256, one block
  __shared__ int ws[4];
  int i = threadIdx.x;
  int lane = i & 63, wid = i >> 6;
  int v = (i < nb) ? bsum[i] : 0;
  int s = v;
#pragma unroll
  for (int off = 1; off < 64; off <<= 1) {
    int t = __shfl_up(s, off);
    if (lane >= off) s += t;
  }
  if (lane == 63) ws[wid] = s;
  __syncthreads();
  int add = 0;
  if (wid > 0) add += ws[0];
  if (wid > 1) add += ws[1];
  if (wid > 2) add += ws[2];
  if (i < nb) bsum[i] = s - v + add;  // exclusive block prefix
}

// scatter: global position = local scan + block prefix (scan_c folded in)
__global__ void k_scatter(int* __restrict__ cnt, const int* __restrict__ bsum,
                          const int* __restrict__ ei, const float* __restrict__ w,
                          const float* __restrict__ dis, uint2* __restrict__ pr, int nE) {
  int i = blockIdx.x * blockDim.x + threadIdx.x;
  if (i < nE) {
    int r = ei[i];
    int c = ei[nE + i];
    int pos = atomicAdd(&cnt[c], 1) + bsum[c >> 8];
    float ww = dis[r] * w[i] * dis[c];
    pr[pos] = make_uint2((unsigned)r, __builtin_bit_cast(unsigned, ww));
  }
}

// ---------------- gather propagate: bf16 in/out, 16B granules, 4x unrolled ----------------
// endp holds block-local ends; true end = endp[v] + bsum[v>>8].
template<int NSQ>  // uint4 granules per row
__global__ void k_gather(const unsigned short* __restrict__ X, const int* __restrict__ endp,
                         const int* __restrict__ bsum, const uint2* __restrict__ pr,
                         const float* __restrict__ dis, unsigned short* __restrict__ out, int n) {
  int tid = blockIdx.x * blockDim.x + threadIdx.x;
  int v = tid / NSQ;
  int s = tid - v * NSQ;
  if (v >= n) return;
  int beg = (v == 0) ? 0 : endp[v - 1] + bsum[(v - 1) >> 8];
  int end = endp[v] + bsum[v >> 8];
  const uint4* Xr = reinterpret_cast<const uint4*>(X);
  float d = dis[v];
  float sw = d * d;
  float acc[8];
  {
    uint4 q = Xr[(size_t)v * NSQ + s];
    acc[0] = blo(q.x) * sw; acc[1] = bhi(q.x) * sw;
    acc[2] = blo(q.y) * sw; acc[3] = bhi(q.y) * sw;
    acc[4] = blo(q.z) * sw; acc[5] = bhi(q.z) * sw;
    acc[6] = blo(q.w) * sw; acc[7] = bhi(q.w) * sw;
  }
  int e = beg;
  for (; e + 4 <= end; e += 4) {
    uint2 p0 = pr[e], p1 = pr[e + 1], p2 = pr[e + 2], p3 = pr[e + 3];
    uint4 q0 = Xr[(size_t)p0.x * NSQ + s];
    uint4 q1 = Xr[(size_t)p1.x * NSQ + s];
    uint4 q2 = Xr[(size_t)p2.x * NSQ + s];
    uint4 q3 = Xr[(size_t)p3.x * NSQ + s];
    fma8(q0, __builtin_bit_cast(float, p0.y), acc);
    fma8(q1, __builtin_bit_cast(float, p1.y), acc);
    fma8(q2, __builtin_bit_cast(float, p2.y), acc);
    fma8(q3, __builtin_bit_cast(float, p3.y), acc);
  }
  for (; e < end; ++e) {
    uint2 p = pr[e];
    uint4 q = Xr[(size_t)p.x * NSQ + s];
    fma8(q, __builtin_bit_cast(float, p.y), acc);
  }
  uint4 o;
  o.x = pk2(acc[0], acc[1]);
  o.y = pk2(acc[2], acc[3]);
  o.z = pk2(acc[4], acc[5]);
  o.w = pk2(acc[6], acc[7]);
  reinterpret_cast<uint4*>(out)[(size_t)v * NSQ + s] = o;
}

// ---------------- bf16 MFMA GEMM (m97 structure) ----------------
// STATS: fused per-column BatchNorm sum / sum-of-squares on the f32 accumulators.
template<bool STATS>
__global__ __launch_bounds__(256) void k_gemm(const unsigned short* __restrict__ A,
    const unsigned short* __restrict__ BT, unsigned short* __restrict__ C,
    float* __restrict__ s1g, float* __restrict__ s2g,
    int M, int Nlog, int K, int ntiles, int nwg) {
  constexpr int BK = 64;
  __shared__ unsigned short lA[(BK / 8) * 128 * 8];  // 16 KB
  __shared__ unsigned short lB[(BK / 8) * 128 * 8];
  __shared__ float sS[128], sQ[128];

  int p = blockIdx.x;
  int xcd = p & 7, idx = p >> 3;
  int q8 = nwg >> 3, r8 = nwg & 7;
  int logical = (xcd < r8 ? xcd * (q8 + 1) : r8 * (q8 + 1) + (xcd - r8) * q8) + idx;
  const int nt = logical % ntiles;
  const int mt = logical / ntiles;
  const int m0 = mt * 128, n0 = nt * 128;

  const int tid = threadIdx.x, lane = tid & 63, wid = tid >> 6;
  const int wr = wid >> 1, wc = wid & 1;
  const int fr = lane & 15, fq = lane >> 4;

  if constexpr (STATS) {
    if (tid < 128) { sS[tid] = 0.f; sQ[tid] = 0.f; }  // covered by first K-loop barrier
  }

  int arow[4], brow[4], k8s[4];
#pragma unroll
  for (int j = 0; j < 4; ++j) {
    int g = tid + 256 * j;
    int row = g & 127;
    k8s[j] = g >> 7;
    int ar = m0 + row;
    arow[j] = (ar < M) ? ar : (M - 1);  // clamp: in-bounds, result discarded
    brow[j] = n0 + row;                 // BT padded: always valid
  }

  f32x4 acc[4][4] = {};

  for (int k0 = 0; k0 < K; k0 += BK) {
    __syncthreads();
#pragma unroll
    for (int j = 0; j < 4; ++j) {
      int g = tid + 256 * j;
      gload16(A  + (size_t)arow[j] * K + k0 + k8s[j] * 8, &lA[g * 8]);
      gload16(BT + (size_t)brow[j] * K + k0 + k8s[j] * 8, &lB[g * 8]);
    }
    __syncthreads();
#pragma unroll
    for (int step = 0; step < 2; ++step) {
      bf16x8 af[4], bf[4];
#pragma unroll
      for (int m = 0; m < 4; ++m)
        af[m] = *reinterpret_cast<const bf16x8*>(
            &lA[(((step * 4 + fq) << 7) + wr * 64 + m * 16 + fr) * 8]);
#pragma unroll
      for (int nn = 0; nn < 4; ++nn)
        bf[nn] = *reinterpret_cast<const bf16x8*>(
            &lB[(((step * 4 + fq) << 7) + wc * 64 + nn * 16 + fr) * 8]);
#pragma unroll
      for (int m = 0; m < 4; ++m)
#pragma unroll
        for (int nn = 0; nn < 4; ++nn)
          acc[m][nn] = __builtin_amdgcn_mfma_f32_16x16x32_bf16(af[m], bf[nn], acc[m][nn], 0, 0, 0);
    }
  }

#pragma unroll
  for (int m = 0; m < 4; ++m) {
#pragma unroll
    for (int r = 0; r < 4; ++r) {
      int row = m0 + wr * 64 + m * 16 + fq * 4 + r;
      if (row >= M) continue;
#pragma unroll
      for (int nn = 0; nn < 4; ++nn) {
        int col = n0 + wc * 64 + nn * 16 + fr;
        if (col < Nlog)
          C[(size_t)row * Nlog + col] = f2bf(acc[m][nn][r]);
      }
    }
  }

  if constexpr (STATS) {
    float ps[4] = {}, pq[4] = {};
#pragma unroll
    for (int m = 0; m < 4; ++m) {
#pragma unroll
      for (int r = 0; r < 4; ++r) {
        int row = m0 + wr * 64 + m * 16 + fq * 4 + r;
        if (row < M) {
#pragma unroll
          for (int nn = 0; nn < 4; ++nn) {
            float v = acc[m][nn][r];
            ps[nn] += v;
            pq[nn] = fmaf(v, v, pq[nn]);
          }
        }
      }
    }
#pragma unroll
    for (int nn = 0; nn < 4; ++nn) {
      int cl = wc * 64 + nn * 16 + fr;
      atomicAdd(&sS[cl], ps[nn]);  // LDS float atomic
      atomicAdd(&sQ[cl], pq[nn]);
    }
    __syncthreads();
    if (tid < 128) {
      atomAddF(&s1g[n0 + tid], sS[tid]);
      atomAddF(&s2g[n0 + tid], sQ[tid]);
    }
  }
}

// ---------------- coalesced BatchNorm stats (layer 2) ----------------
template<int C>
__global__ __launch_bounds__(256) void k_bn_stats_co(const unsigned short* __restrict__ H,
                                                     float* __restrict__ s1, float* __restrict__ s2,
                                                     int n, int rpb) {
  constexpr int G = C / 8;
  __shared__ float redS[3][G][8];
  __shared__ float redQ[3][G][8];
  const int g = threadIdx.x & 63;
  const int rr = threadIdx.x >> 6;
  int r0 = blockIdx.x * rpb;
  int r1 = r0 + rpb; if (r1 > n) r1 = n;
  float sa[8] = {}, sq[8] = {};
  if (g < G) {
    for (int r = r0 + rr; r < r1; r += 4) {
      uint4 q = *reinterpret_cast<const uint4*>(H + (size_t)r * C + g * 8);
      float v[8] = {blo(q.x), bhi(q.x), blo(q.y), bhi(q.y),
                    blo(q.z), bhi(q.z), blo(q.w), bhi(q.w)};
#pragma unroll
      for (int j = 0; j < 8; ++j) {
        sa[j] += v[j];
        sq[j] = fmaf(v[j], v[j], sq[j]);
      }
    }
    if (rr > 0) {
#pragma unroll
      for (int j = 0; j < 8; ++j) {
        redS[rr - 1][g][j] = sa[j];
        redQ[rr - 1][g][j] = sq[j];
      }
    }
  }
  __syncthreads();
  if (rr == 0 && g < G) {
#pragma unroll
    for (int j = 0; j < 8; ++j) {
      float ts = sa[j] + redS[0][g][j] + redS[1][g][j] + redS[2][g][j];
      float tq = sq[j] + redQ[0][g][j] + redQ[1][g][j] + redQ[2][g][j];
      atomAddF(&s1[g * 8 + j], ts);
      atomAddF(&s2[g * 8 + j], tq);
    }
  }
}

// in-place BN+ReLU on bf16 buffer with fused finalize (reads raw stats). C power of 2.
template<int C>
__global__ void k_bn_apply_relu_bf16(unsigned short* __restrict__ H,
                                     const float* __restrict__ s1, const float* __restrict__ s2,
                                     const float* __restrict__ g, const float* __restrict__ be,
                                     float invN, int total8) {
  int i = blockIdx.x * blockDim.x + threadIdx.x;
  if (i >= total8) return;
  int c = (i * 8) & (C - 1);
  float sc[8], sh[8];
#pragma unroll
  for (int j = 0; j < 8; ++j) {  // inline bn_finalize (L2-hot 2KB arrays)
    float mean = s1[c + j] * invN;
    float var = fmaxf(s2[c + j] * invN - mean * mean, 0.f);
    float s = g[c + j] * rsqrtf(var + kEps);
    sc[j] = s;
    sh[j] = be[c + j] - mean * s;
  }
  uint4 q = reinterpret_cast<uint4*>(H)[i];
  unsigned w[4] = {q.x, q.y, q.z, q.w};
  unsigned o[4];
#pragma unroll
  for (int j = 0; j < 4; ++j) {
    float lo = fmaxf(fmaf(blo(w[j]), sc[j * 2],     sh[j * 2]),     0.f);
    float hi = fmaxf(fmaf(bhi(w[j]), sc[j * 2 + 1], sh[j * 2 + 1]), 0.f);
    o[j] = pk2(lo, hi);
  }
  reinterpret_cast<uint4*>(H)[i] = make_uint4(o[0], o[1], o[2], o[3]);
}

// ---------------- head: BN2-finalize + apply + relu + @Wl + bl + relu + log_softmax ----------------
__global__ __launch_bounds__(256) void k_head(const unsigned short* __restrict__ H,
    const float* __restrict__ s1, const float* __restrict__ s2,
    const float* __restrict__ g2, const float* __restrict__ be2,
    const float* __restrict__ Wl, const float* __restrict__ bl,
    float* __restrict__ out, int n, float invN) {
  __shared__ float sW[kH2 * kOut];
  __shared__ float sScale[kH2], sShift[kH2];
  for (int i = threadIdx.x; i < kH2 * kOut; i += blockDim.x) sW[i] = Wl[i];
  for (int i = threadIdx.x; i < kH2; i += blockDim.x) {  // fused bn_finalize2
    float mean = s1[i] * invN;
    float var = fmaxf(s2[i] * invN - mean * mean, 0.f);
    float sc = g2[i] * rsqrtf(var + kEps);
    sScale[i] = sc;
    sShift[i] = be2[i] - mean * sc;
  }
  __syncthreads();
  float blv[kOut];
#pragma unroll
  for (int j = 0; j < kOut; ++j) blv[j] = bl[j];
  const int lane = threadIdx.x & 63;
  const int wid = (blockIdx.x * blockDim.x + threadIdx.x) >> 6;
  const int nw  = (gridDim.x * blockDim.x) >> 6;
  for (int node = wid; node < n; node += nw) {
    const unsigned short* hrow = H + (size_t)node * kH2p;
    float acc[kOut] = {};
    for (int k = lane; k < kH2; k += 64) {
      float v = fmaxf(fmaf(bf2f(hrow[k]), sScale[k], sShift[k]), 0.f);
      const float* wr = sW + k * kOut;
#pragma unroll
      for (int j = 0; j < kOut; ++j) acc[j] = fmaf(v, wr[j], acc[j]);
    }
#pragma unroll
    for (int j = 0; j < kOut; ++j) {
      float v = acc[j];
      for (int off = 32; off > 0; off >>= 1) v += __shfl_down(v, off);
      acc[j] = v;
    }
    if (lane == 0) {
      float vv[kOut], m = -1e30f;
#pragma unroll
      for (int j = 0; j < kOut; ++j) {
        vv[j] = fmaxf(acc[j] + blv[j], 0.f);
        m = fmaxf(m, vv[j]);
      }
      float s = 0.f;
#pragma unroll
      for (int j = 0; j < kOut; ++j) s += expf(vv[j] - m);
      float lse = m + logf(s);
      float* o = out + (size_t)node * kOut;
#pragma unroll
      for (int j = 0; j < kOut; ++j) o[j] = vv[j] - lse;
    }
  }
}

}  // namespace

extern "C" void kernel_launch(void* const* d_in, const int* in_sizes, int n_in,
                              void* d_out, int out_size, void* d_ws, size_t ws_size,
                              hipStream_t stream) {
  const float* x   = (const float*)d_in[0];
  const int*   ei  = (const int*)d_in[1];
  const float* ew  = (const float*)d_in[2];
  const float* W1  = (const float*)d_in[3];
  // d_in[4] = b1: constant per column -> cancelled by BN1 mean subtraction
  const float* g1  = (const float*)d_in[5];
  const float* be1 = (const float*)d_in[6];
  const float* W2  = (const float*)d_in[7];
  // d_in[8] = b2: cancelled by BN2
  const float* g2  = (const float*)d_in[9];
  const float* be2 = (const float*)d_in[10];
  const float* Wl  = (const float*)d_in[11];
  const float* bl  = (const float*)d_in[12];
  float* out = (float*)d_out;
  float* ws  = (float*)d_ws;

  const int n = in_sizes[0] / kIn;  // 50000
  const int e = in_sizes[1] / 2;    // 800000

  // workspace (float units), ~145 MB:
  float* dis = ws;                                          // 50048 (deg -> dis in place)
  int*   cnt = (int*)(ws + 50048);                          // 50048
  uint2* pr  = (uint2*)(ws + 100096);                       // 800000 pairs
  float* st  = ws + 1700096;                                // 4096
  float* s1a = st,        *s2a = st + 512;
  float* s1b = st + 2048, *s2b = st + 2560;
  int*   bsum = (int*)(ws + 1704192);                       // 512
  unsigned short* xbf = (unsigned short*)(ws + 1704704);    // [n][128] = 3.2M fl
  unsigned short* W1T = (unsigned short*)(ws + 4904704);    // 512x128 = 32768 fl
  unsigned short* W2T = (unsigned short*)(ws + 4937472);    // 384x512 = 98304 fl
  unsigned short* agg1 = (unsigned short*)(ws + 5035776);   // [n][128] = 3.2M fl
  unsigned short* h1   = (unsigned short*)(ws + 8235776);   // [n][512] = 12.8M fl
  unsigned short* t2   = (unsigned short*)(ws + 21035776);  // [n][304] = 7.6M fl
  unsigned short* agg2 = (unsigned short*)(ws + 28635776);  // [n][304] = 7.6M fl

  constexpr int TPB = 256;
  const int nb = (n + 255) / 256;   // scan blocks (196 <= 256)
  const int rpb = (n + 255) / 256;  // stats rows per block

  // ---- init (deg+cnt contiguous) + merged prep/deg + CSC build ----
  hipMemsetAsync(ws, 0, (size_t)100096 * sizeof(float), stream);
  {
    int edgeBlocks = (e + TPB - 1) / TPB;          // 3125
    int convBlocks = (n * 16 + TPB - 1) / TPB;     // 3125
    k_prep_deg<<<edgeBlocks + convBlocks, TPB, 0, stream>>>(
        x, xbf, st, W1, W1T, W2, W2T, dis, cnt, ei, ew, n, e, edgeBlocks);
  }
  k_scan_a<<<nb, 256, 0, stream>>>(cnt, bsum, dis, n);
  k_scan_b<<<1, 256, 0, stream>>>(bsum, nb);
  k_scatter<<<(e + TPB - 1) / TPB, TPB, 0, stream>>>(cnt, bsum, ei, ew, dis, pr, e);

  const int mtiles = (n + 127) / 128;  // 391

  // ---- layer 1: agg1 = A(xbf); h1 = bf16(agg1@W1) + fused BN1 stats; BN+ReLU in place ----
  {
    int tot = n * (kIn / 8);
    k_gather<kIn / 8><<<(tot + TPB - 1) / TPB, TPB, 0, stream>>>(xbf, cnt, bsum, pr, dis, agg1, n);
  }
  {
    int ntiles = kH1 / 128;            // 4
    int nwg = mtiles * ntiles;
    k_gemm<true><<<nwg, 256, 0, stream>>>(agg1, W1T, h1, s1a, s2a, n, kH1, kIn, ntiles, nwg);
  }
  k_bn_apply_relu_bf16<kH1><<<((n * (kH1 / 8)) + TPB - 1) / TPB, TPB, 0, stream>>>(
      h1, s1a, s2a, g1, be1, 1.0f / n, n * (kH1 / 8));

  // ---- layer 2: t2 = bf16(h1@W2); agg2 = A(t2); BN2 stats ----
  {
    int ntiles = kW2R / 128;           // 3
    int nwg = mtiles * ntiles;
    k_gemm<false><<<nwg, 256, 0, stream>>>(h1, W2T, t2, nullptr, nullptr, n, kH2p, kH1, ntiles, nwg);
  }
  {
    int tot = n * (kH2p / 8);
    k_gather<kH2p / 8><<<(tot + TPB - 1) / TPB, TPB, 0, stream>>>(t2, cnt, bsum, pr, dis, agg2, n);
  }
  k_bn_stats_co<kH2p><<<256, 256, 0, stream>>>(agg2, s1b, s2b, n, rpb);

  // ---- head (fused BN2 finalize) ----
  k_head<<<1024, 256, 0, stream>>>(agg2, s1b, s2b, g2, be2, Wl, bl, out, n, 1.0f / n);
}

// Round 12
// 450.303 us; speedup vs baseline: 1.0775x; 1.0775x over previous
//
#include <hip/hip_runtime.h>
#include <math.h>

namespace {

constexpr int kIn  = 128;
constexpr int kH1  = 512;
constexpr int kH2  = 300;
constexpr int kH2p = 304;   // padded to 16B granule
constexpr int kW2R = 384;   // W2T padded rows (3 x 128 col-tiles)
constexpr int kOut = 10;
constexpr float kEps = 1e-5f;

typedef __attribute__((ext_vector_type(8))) short bf16x8;
typedef __attribute__((ext_vector_type(4))) float f32x4;

__device__ __forceinline__ void atomAddF(float* p, float v) { unsafeAtomicAdd(p, v); }

__device__ __forceinline__ unsigned short f2bf(float f) {  // RNE f32->bf16
  unsigned u = __builtin_bit_cast(unsigned, f);
  unsigned r = u + 0x7fffu + ((u >> 16) & 1u);
  return (unsigned short)(r >> 16);
}
__device__ __forceinline__ float bf2f(unsigned short h) {
  return __builtin_bit_cast(float, (unsigned)h << 16);
}
__device__ __forceinline__ float blo(unsigned u) { return __builtin_bit_cast(float, u << 16); }
__device__ __forceinline__ float bhi(unsigned u) { return __builtin_bit_cast(float, u & 0xffff0000u); }
__device__ __forceinline__ unsigned pk2(float a, float b) {
  return (unsigned)f2bf(a) | ((unsigned)f2bf(b) << 16);
}

// async global(16B) -> LDS DMA; dest = wave-uniform base + lane*16
__device__ __forceinline__ void gload16(const unsigned short* g, unsigned short* l) {
  __builtin_amdgcn_global_load_lds(
      (const __attribute__((address_space(1))) unsigned int*)g,
      (__attribute__((address_space(3))) unsigned int*)l, 16, 0, 0);
}

__device__ __forceinline__ void fma8(const uint4& q, float w, float* acc) {
  acc[0] = fmaf(blo(q.x), w, acc[0]);
  acc[1] = fmaf(bhi(q.x), w, acc[1]);
  acc[2] = fmaf(blo(q.y), w, acc[2]);
  acc[3] = fmaf(bhi(q.y), w, acc[3]);
  acc[4] = fmaf(blo(q.z), w, acc[4]);
  acc[5] = fmaf(bhi(q.z), w, acc[5]);
  acc[6] = fmaf(blo(q.w), w, acc[6]);
  acc[7] = fmaf(bhi(q.w), w, acc[7]);
}

// ---------------- merged prep + degree/count ----------------
// Blocks [0, edgeBlocks): ONE packed u64 atomic per edge:
//   cnt64[c] += (1 << 40) + round(w * 2^24)   (count in high bits, fixed-point
//   weight-sum in low bits; sum < 2^30 so no carry into the count field).
// Blocks [edgeBlocks, ..): conversions (st zero, W1T, W2T, xbf).
// cnt64 pre-zeroed by hipMemsetAsync; self-loop folded into rsqrt(sum+1) later.
__global__ void k_prep_deg(const float* __restrict__ x, unsigned short* __restrict__ xbf,
                           float* __restrict__ st,
                           const float* __restrict__ W1, unsigned short* __restrict__ W1T,
                           const float* __restrict__ W2, unsigned short* __restrict__ W2T,
                           unsigned long long* __restrict__ cnt64,
                           const int* __restrict__ ei, const float* __restrict__ ew,
                           int n, int nE, int edgeBlocks) {
  if ((int)blockIdx.x < edgeBlocks) {
    int i = blockIdx.x * blockDim.x + threadIdx.x;
    if (i < nE) {
      int c = ei[nE + i];
      unsigned long long v =
          (1ULL << 40) + (unsigned long long)__float2uint_rn(ew[i] * 16777216.0f);
      atomicAdd(&cnt64[c], v);
    }
    return;
  }
  int i = (blockIdx.x - edgeBlocks) * blockDim.x + threadIdx.x;
  if (i < 4096) st[i] = 0.f;
  if (i < kIn * kH1) {  // W1T[512][128]
    int nn = i / kIn, k = i - nn * kIn;
    W1T[i] = f2bf(W1[(size_t)k * kH1 + nn]);
  }
  if (i < kW2R * kH1) {  // W2T[384][512], rows >=300 zero
    int nn = i / kH1, k = i - nn * kH1;
    W2T[i] = (nn < kH2) ? f2bf(W2[(size_t)k * kH2 + nn]) : (unsigned short)0;
  }
  if (i < n * 16) {  // xbf row-major [n][128]
    int node = i >> 4, g = i & 15;
    const float4* xp = reinterpret_cast<const float4*>(x + (size_t)node * kIn + g * 8);
    float4 v0 = xp[0], v1 = xp[1];
    uint4 o;
    o.x = pk2(v0.x, v0.y); o.y = pk2(v0.z, v0.w);
    o.z = pk2(v1.x, v1.y); o.w = pk2(v1.z, v1.w);
    reinterpret_cast<uint4*>(xbf)[i] = o;
  }
}

// ---------------- 2-phase scan: unpack cnt64 -> (dis, local scan), block sums ----------------
__global__ void k_scan_a(const unsigned long long* __restrict__ cnt64, int* __restrict__ cnt,
                         int* __restrict__ bsum, float* __restrict__ dis, int n) {
  __shared__ int ws[4];
  int i = blockIdx.x * 256 + threadIdx.x;
  int lane = threadIdx.x & 63, wid = threadIdx.x >> 6;
  unsigned long long cv = (i < n) ? cnt64[i] : 0ULL;
  if (i < n)  // deg = fixed-point weight sum + 1 (self loop)
    dis[i] = rsqrtf(1.0f + (float)(unsigned)cv * (1.0f / 16777216.0f));
  int v = (int)(cv >> 40);
  int s = v;
#pragma unroll
  for (int off = 1; off < 64; off <<= 1) {
    int t = __shfl_up(s, off);
    if (lane >= off) s += t;
  }
  if (lane == 63) ws[wid] = s;
  __syncthreads();
  int add = 0;
  if (wid > 0) add += ws[0];
  if (wid > 1) add += ws[1];
  if (wid > 2) add += ws[2];
  if (i < n) cnt[i] = s - v + add;  // block-local exclusive scan
  if (threadIdx.x == 255) bsum[blockIdx.x] = add + s;
}

__global__ void k_scan_b(int* __restrict__ bsum, int nb) {  // nb <= 256, one block
  __shared__ int ws[4];
  int i = threadIdx.x;
  int lane = i & 63, wid = i >> 6;
  int v = (i < nb) ? bsum[i] : 0;
  int s = v;
#pragma unroll
  for (int off = 1; off < 64; off <<= 1) {
    int t = __shfl_up(s, off);
    if (lane >= off) s += t;
  }
  if (lane == 63) ws[wid] = s;
  __syncthreads();
  int add = 0;
  if (wid > 0) add += ws[0];
  if (wid > 1) add += ws[1];
  if (wid > 2) add += ws[2];
  if (i < nb) bsum[i] = s - v + add;  // exclusive block prefix
}

// scatter: global position = local scan + block prefix
__global__ void k_scatter(int* __restrict__ cnt, const int* __restrict__ bsum,
                          const int* __restrict__ ei, const float* __restrict__ w,
                          const float* __restrict__ dis, uint2* __restrict__ pr, int nE) {
  int i = blockIdx.x * blockDim.x + threadIdx.x;
  if (i < nE) {
    int r = ei[i];
    int c = ei[nE + i];
    int pos = atomicAdd(&cnt[c], 1) + bsum[c >> 8];
    float ww = dis[r] * w[i] * dis[c];
    pr[pos] = make_uint2((unsigned)r, __builtin_bit_cast(unsigned, ww));
  }
}

// ---------------- gather propagate: bf16 in/out, 16B granules, 4x unrolled ----------------
// endp holds block-local ends; true end = endp[v] + bsum[v>>8].
template<int NSQ>  // uint4 granules per row
__global__ void k_gather(const unsigned short* __restrict__ X, const int* __restrict__ endp,
                         const int* __restrict__ bsum, const uint2* __restrict__ pr,
                         const float* __restrict__ dis, unsigned short* __restrict__ out, int n) {
  int tid = blockIdx.x * blockDim.x + threadIdx.x;
  int v = tid / NSQ;
  int s = tid - v * NSQ;
  if (v >= n) return;
  int beg = (v == 0) ? 0 : endp[v - 1] + bsum[(v - 1) >> 8];
  int end = endp[v] + bsum[v >> 8];
  const uint4* Xr = reinterpret_cast<const uint4*>(X);
  float d = dis[v];
  float sw = d * d;
  float acc[8];
  {
    uint4 q = Xr[(size_t)v * NSQ + s];
    acc[0] = blo(q.x) * sw; acc[1] = bhi(q.x) * sw;
    acc[2] = blo(q.y) * sw; acc[3] = bhi(q.y) * sw;
    acc[4] = blo(q.z) * sw; acc[5] = bhi(q.z) * sw;
    acc[6] = blo(q.w) * sw; acc[7] = bhi(q.w) * sw;
  }
  int e = beg;
  for (; e + 4 <= end; e += 4) {
    uint2 p0 = pr[e], p1 = pr[e + 1], p2 = pr[e + 2], p3 = pr[e + 3];
    uint4 q0 = Xr[(size_t)p0.x * NSQ + s];
    uint4 q1 = Xr[(size_t)p1.x * NSQ + s];
    uint4 q2 = Xr[(size_t)p2.x * NSQ + s];
    uint4 q3 = Xr[(size_t)p3.x * NSQ + s];
    fma8(q0, __builtin_bit_cast(float, p0.y), acc);
    fma8(q1, __builtin_bit_cast(float, p1.y), acc);
    fma8(q2, __builtin_bit_cast(float, p2.y), acc);
    fma8(q3, __builtin_bit_cast(float, p3.y), acc);
  }
  for (; e < end; ++e) {
    uint2 p = pr[e];
    uint4 q = Xr[(size_t)p.x * NSQ + s];
    fma8(q, __builtin_bit_cast(float, p.y), acc);
  }
  uint4 o;
  o.x = pk2(acc[0], acc[1]);
  o.y = pk2(acc[2], acc[3]);
  o.z = pk2(acc[4], acc[5]);
  o.w = pk2(acc[6], acc[7]);
  reinterpret_cast<uint4*>(out)[(size_t)v * NSQ + s] = o;
}

// ---------------- bf16 MFMA GEMM (m97 structure) ----------------
// STATS: fused per-column BatchNorm sum / sum-of-squares on the f32 accumulators.
template<bool STATS>
__global__ __launch_bounds__(256) void k_gemm(const unsigned short* __restrict__ A,
    const unsigned short* __restrict__ BT, unsigned short* __restrict__ C,
    float* __restrict__ s1g, float* __restrict__ s2g,
    int M, int Nlog, int K, int ntiles, int nwg) {
  constexpr int BK = 64;
  __shared__ unsigned short lA[(BK / 8) * 128 * 8];  // 16 KB
  __shared__ unsigned short lB[(BK / 8) * 128 * 8];
  __shared__ float sS[128], sQ[128];

  int p = blockIdx.x;
  int xcd = p & 7, idx = p >> 3;
  int q8 = nwg >> 3, r8 = nwg & 7;
  int logical = (xcd < r8 ? xcd * (q8 + 1) : r8 * (q8 + 1) + (xcd - r8) * q8) + idx;
  const int nt = logical % ntiles;
  const int mt = logical / ntiles;
  const int m0 = mt * 128, n0 = nt * 128;

  const int tid = threadIdx.x, lane = tid & 63, wid = tid >> 6;
  const int wr = wid >> 1, wc = wid & 1;
  const int fr = lane & 15, fq = lane >> 4;

  if constexpr (STATS) {
    if (tid < 128) { sS[tid] = 0.f; sQ[tid] = 0.f; }  // covered by first K-loop barrier
  }

  int arow[4], brow[4], k8s[4];
#pragma unroll
  for (int j = 0; j < 4; ++j) {
    int g = tid + 256 * j;
    int row = g & 127;
    k8s[j] = g >> 7;
    int ar = m0 + row;
    arow[j] = (ar < M) ? ar : (M - 1);  // clamp: in-bounds, result discarded
    brow[j] = n0 + row;                 // BT padded: always valid
  }

  f32x4 acc[4][4] = {};

  for (int k0 = 0; k0 < K; k0 += BK) {
    __syncthreads();
#pragma unroll
    for (int j = 0; j < 4; ++j) {
      int g = tid + 256 * j;
      gload16(A  + (size_t)arow[j] * K + k0 + k8s[j] * 8, &lA[g * 8]);
      gload16(BT + (size_t)brow[j] * K + k0 + k8s[j] * 8, &lB[g * 8]);
    }
    __syncthreads();
#pragma unroll
    for (int step = 0; step < 2; ++step) {
      bf16x8 af[4], bf[4];
#pragma unroll
      for (int m = 0; m < 4; ++m)
        af[m] = *reinterpret_cast<const bf16x8*>(
            &lA[(((step * 4 + fq) << 7) + wr * 64 + m * 16 + fr) * 8]);
#pragma unroll
      for (int nn = 0; nn < 4; ++nn)
        bf[nn] = *reinterpret_cast<const bf16x8*>(
            &lB[(((step * 4 + fq) << 7) + wc * 64 + nn * 16 + fr) * 8]);
#pragma unroll
      for (int m = 0; m < 4; ++m)
#pragma unroll
        for (int nn = 0; nn < 4; ++nn)
          acc[m][nn] = __builtin_amdgcn_mfma_f32_16x16x32_bf16(af[m], bf[nn], acc[m][nn], 0, 0, 0);
    }
  }

#pragma unroll
  for (int m = 0; m < 4; ++m) {
#pragma unroll
    for (int r = 0; r < 4; ++r) {
      int row = m0 + wr * 64 + m * 16 + fq * 4 + r;
      if (row >= M) continue;
#pragma unroll
      for (int nn = 0; nn < 4; ++nn) {
        int col = n0 + wc * 64 + nn * 16 + fr;
        if (col < Nlog)
          C[(size_t)row * Nlog + col] = f2bf(acc[m][nn][r]);
      }
    }
  }

  if constexpr (STATS) {
    float ps[4] = {}, pq[4] = {};
#pragma unroll
    for (int m = 0; m < 4; ++m) {
#pragma unroll
      for (int r = 0; r < 4; ++r) {
        int row = m0 + wr * 64 + m * 16 + fq * 4 + r;
        if (row < M) {
#pragma unroll
          for (int nn = 0; nn < 4; ++nn) {
            float v = acc[m][nn][r];
            ps[nn] += v;
            pq[nn] = fmaf(v, v, pq[nn]);
          }
        }
      }
    }
#pragma unroll
    for (int nn = 0; nn < 4; ++nn) {
      int cl = wc * 64 + nn * 16 + fr;
      atomicAdd(&sS[cl], ps[nn]);  // LDS float atomic
      atomicAdd(&sQ[cl], pq[nn]);
    }
    __syncthreads();
    if (tid < 128) {
      atomAddF(&s1g[n0 + tid], sS[tid]);
      atomAddF(&s2g[n0 + tid], sQ[tid]);
    }
  }
}

// ---------------- coalesced BatchNorm stats (layer 2) ----------------
template<int C>
__global__ __launch_bounds__(256) void k_bn_stats_co(const unsigned short* __restrict__ H,
                                                     float* __restrict__ s1, float* __restrict__ s2,
                                                     int n, int rpb) {
  constexpr int G = C / 8;
  __shared__ float redS[3][G][8];
  __shared__ float redQ[3][G][8];
  const int g = threadIdx.x & 63;
  const int rr = threadIdx.x >> 6;
  int r0 = blockIdx.x * rpb;
  int r1 = r0 + rpb; if (r1 > n) r1 = n;
  float sa[8] = {}, sq[8] = {};
  if (g < G) {
    for (int r = r0 + rr; r < r1; r += 4) {
      uint4 q = *reinterpret_cast<const uint4*>(H + (size_t)r * C + g * 8);
      float v[8] = {blo(q.x), bhi(q.x), blo(q.y), bhi(q.y),
                    blo(q.z), bhi(q.z), blo(q.w), bhi(q.w)};
#pragma unroll
      for (int j = 0; j < 8; ++j) {
        sa[j] += v[j];
        sq[j] = fmaf(v[j], v[j], sq[j]);
      }
    }
    if (rr > 0) {
#pragma unroll
      for (int j = 0; j < 8; ++j) {
        redS[rr - 1][g][j] = sa[j];
        redQ[rr - 1][g][j] = sq[j];
      }
    }
  }
  __syncthreads();
  if (rr == 0 && g < G) {
#pragma unroll
    for (int j = 0; j < 8; ++j) {
      float ts = sa[j] + redS[0][g][j] + redS[1][g][j] + redS[2][g][j];
      float tq = sq[j] + redQ[0][g][j] + redQ[1][g][j] + redQ[2][g][j];
      atomAddF(&s1[g * 8 + j], ts);
      atomAddF(&s2[g * 8 + j], tq);
    }
  }
}

// in-place BN+ReLU on bf16 buffer with fused finalize (reads raw stats). C power of 2.
template<int C>
__global__ void k_bn_apply_relu_bf16(unsigned short* __restrict__ H,
                                     const float* __restrict__ s1, const float* __restrict__ s2,
                                     const float* __restrict__ g, const float* __restrict__ be,
                                     float invN, int total8) {
  int i = blockIdx.x * blockDim.x + threadIdx.x;
  if (i >= total8) return;
  int c = (i * 8) & (C - 1);
  float sc[8], sh[8];
#pragma unroll
  for (int j = 0; j < 8; ++j) {  // inline bn_finalize (L2-hot 2KB arrays)
    float mean = s1[c + j] * invN;
    float var = fmaxf(s2[c + j] * invN - mean * mean, 0.f);
    float s = g[c + j] * rsqrtf(var + kEps);
    sc[j] = s;
    sh[j] = be[c + j] - mean * s;
  }
  uint4 q = reinterpret_cast<uint4*>(H)[i];
  unsigned w[4] = {q.x, q.y, q.z, q.w};
  unsigned o[4];
#pragma unroll
  for (int j = 0; j < 4; ++j) {
    float lo = fmaxf(fmaf(blo(w[j]), sc[j * 2],     sh[j * 2]),     0.f);
    float hi = fmaxf(fmaf(bhi(w[j]), sc[j * 2 + 1], sh[j * 2 + 1]), 0.f);
    o[j] = pk2(lo, hi);
  }
  reinterpret_cast<uint4*>(H)[i] = make_uint4(o[0], o[1], o[2], o[3]);
}

// ---------------- head: BN2-finalize + apply + relu + @Wl + bl + relu + log_softmax ----------------
__global__ __launch_bounds__(256) void k_head(const unsigned short* __restrict__ H,
    const float* __restrict__ s1, const float* __restrict__ s2,
    const float* __restrict__ g2, const float* __restrict__ be2,
    const float* __restrict__ Wl, const float* __restrict__ bl,
    float* __restrict__ out, int n, float invN) {
  __shared__ float sW[kH2 * kOut];
  __shared__ float sScale[kH2], sShift[kH2];
  for (int i = threadIdx.x; i < kH2 * kOut; i += blockDim.x) sW[i] = Wl[i];
  for (int i = threadIdx.x; i < kH2; i += blockDim.x) {  // fused bn_finalize2
    float mean = s1[i] * invN;
    float var = fmaxf(s2[i] * invN - mean * mean, 0.f);
    float sc = g2[i] * rsqrtf(var + kEps);
    sScale[i] = sc;
    sShift[i] = be2[i] - mean * sc;
  }
  __syncthreads();
  float blv[kOut];
#pragma unroll
  for (int j = 0; j < kOut; ++j) blv[j] = bl[j];
  const int lane = threadIdx.x & 63;
  const int wid = (blockIdx.x * blockDim.x + threadIdx.x) >> 6;
  const int nw  = (gridDim.x * blockDim.x) >> 6;
  for (int node = wid; node < n; node += nw) {
    const unsigned short* hrow = H + (size_t)node * kH2p;
    float acc[kOut] = {};
    for (int k = lane; k < kH2; k += 64) {
      float v = fmaxf(fmaf(bf2f(hrow[k]), sScale[k], sShift[k]), 0.f);
      const float* wr = sW + k * kOut;
#pragma unroll
      for (int j = 0; j < kOut; ++j) acc[j] = fmaf(v, wr[j], acc[j]);
    }
#pragma unroll
    for (int j = 0; j < kOut; ++j) {
      float v = acc[j];
      for (int off = 32; off > 0; off >>= 1) v += __shfl_down(v, off);
      acc[j] = v;
    }
    if (lane == 0) {
      float vv[kOut], m = -1e30f;
#pragma unroll
      for (int j = 0; j < kOut; ++j) {
        vv[j] = fmaxf(acc[j] + blv[j], 0.f);
        m = fmaxf(m, vv[j]);
      }
      float s = 0.f;
#pragma unroll
      for (int j = 0; j < kOut; ++j) s += expf(vv[j] - m);
      float lse = m + logf(s);
      float* o = out + (size_t)node * kOut;
#pragma unroll
      for (int j = 0; j < kOut; ++j) o[j] = vv[j] - lse;
    }
  }
}

}  // namespace

extern "C" void kernel_launch(void* const* d_in, const int* in_sizes, int n_in,
                              void* d_out, int out_size, void* d_ws, size_t ws_size,
                              hipStream_t stream) {
  const float* x   = (const float*)d_in[0];
  const int*   ei  = (const int*)d_in[1];
  const float* ew  = (const float*)d_in[2];
  const float* W1  = (const float*)d_in[3];
  // d_in[4] = b1: constant per column -> cancelled by BN1 mean subtraction
  const float* g1  = (const float*)d_in[5];
  const float* be1 = (const float*)d_in[6];
  const float* W2  = (const float*)d_in[7];
  // d_in[8] = b2: cancelled by BN2
  const float* g2  = (const float*)d_in[9];
  const float* be2 = (const float*)d_in[10];
  const float* Wl  = (const float*)d_in[11];
  const float* bl  = (const float*)d_in[12];
  float* out = (float*)d_out;
  float* ws  = (float*)d_ws;

  const int n = in_sizes[0] / kIn;  // 50000
  const int e = in_sizes[1] / 2;    // 800000

  // workspace (float units), ~145 MB:
  float* dis = ws;                                          // 50048
  int*   cnt = (int*)(ws + 50048);                          // 50048
  unsigned long long* cnt64 = (unsigned long long*)(ws + 100096);  // 50048 u64 = 100096 fl
  uint2* pr  = (uint2*)(ws + 200192);                       // 800000 pairs = 1.6M fl
  float* st  = ws + 1800192;                                // 4096
  float* s1a = st,        *s2a = st + 512;
  float* s1b = st + 2048, *s2b = st + 2560;
  int*   bsum = (int*)(ws + 1804288);                       // 512
  unsigned short* xbf = (unsigned short*)(ws + 1804800);    // [n][128] = 3.2M fl
  unsigned short* W1T = (unsigned short*)(ws + 5004800);    // 512x128 = 32768 fl
  unsigned short* W2T = (unsigned short*)(ws + 5037568);    // 384x512 = 98304 fl
  unsigned short* agg1 = (unsigned short*)(ws + 5135872);   // [n][128] = 3.2M fl
  unsigned short* h1   = (unsigned short*)(ws + 8335872);   // [n][512] = 12.8M fl
  unsigned short* t2   = (unsigned short*)(ws + 21135872);  // [n][304] = 7.6M fl
  unsigned short* agg2 = (unsigned short*)(ws + 28735872);  // [n][304] = 7.6M fl

  constexpr int TPB = 256;
  const int nb = (n + 255) / 256;   // scan blocks (196 <= 256)
  const int rpb = (n + 255) / 256;  // stats rows per block

  // ---- init cnt64 + merged prep/deg + CSC build ----
  hipMemsetAsync(cnt64, 0, (size_t)50048 * sizeof(unsigned long long), stream);
  {
    int edgeBlocks = (e + TPB - 1) / TPB;          // 3125
    int convBlocks = (n * 16 + TPB - 1) / TPB;     // 3125
    k_prep_deg<<<edgeBlocks + convBlocks, TPB, 0, stream>>>(
        x, xbf, st, W1, W1T, W2, W2T, cnt64, ei, ew, n, e, edgeBlocks);
  }
  k_scan_a<<<nb, 256, 0, stream>>>(cnt64, cnt, bsum, dis, n);
  k_scan_b<<<1, 256, 0, stream>>>(bsum, nb);
  k_scatter<<<(e + TPB - 1) / TPB, TPB, 0, stream>>>(cnt, bsum, ei, ew, dis, pr, e);

  const int mtiles = (n + 127) / 128;  // 391

  // ---- layer 1: agg1 = A(xbf); h1 = bf16(agg1@W1) + fused BN1 stats; BN+ReLU in place ----
  {
    int tot = n * (kIn / 8);
    k_gather<kIn / 8><<<(tot + TPB - 1) / TPB, TPB, 0, stream>>>(xbf, cnt, bsum, pr, dis, agg1, n);
  }
  {
    int ntiles = kH1 / 128;            // 4
    int nwg = mtiles * ntiles;
    k_gemm<true><<<nwg, 256, 0, stream>>>(agg1, W1T, h1, s1a, s2a, n, kH1, kIn, ntiles, nwg);
  }
  k_bn_apply_relu_bf16<kH1><<<((n * (kH1 / 8)) + TPB - 1) / TPB, TPB, 0, stream>>>(
      h1, s1a, s2a, g1, be1, 1.0f / n, n * (kH1 / 8));

  // ---- layer 2: t2 = bf16(h1@W2); agg2 = A(t2); BN2 stats ----
  {
    int ntiles = kW2R / 128;           // 3
    int nwg = mtiles * ntiles;
    k_gemm<false><<<nwg, 256, 0, stream>>>(h1, W2T, t2, nullptr, nullptr, n, kH2p, kH1, ntiles, nwg);
  }
  {
    int tot = n * (kH2p / 8);
    k_gather<kH2p / 8><<<(tot + TPB - 1) / TPB, TPB, 0, stream>>>(t2, cnt, bsum, pr, dis, agg2, n);
  }
  k_bn_stats_co<kH2p><<<256, 256, 0, stream>>>(agg2, s1b, s2b, n, rpb);

  // ---- head (fused BN2 finalize) ----
  k_head<<<1024, 256, 0, stream>>>(agg2, s1b, s2b, g2, be2, Wl, bl, out, n, 1.0f / n);
}

// Round 13
// 447.131 us; speedup vs baseline: 1.0851x; 1.0071x over previous
//
#include <hip/hip_runtime.h>
#include <math.h>

namespace {

constexpr int kIn  = 128;
constexpr int kH1  = 512;
constexpr int kH2  = 300;
constexpr int kH2p = 304;   // padded to 16B granule
constexpr int kW2R = 384;   // W2T padded rows (3 x 128 col-tiles)
constexpr int kOut = 10;
constexpr float kEps = 1e-5f;

typedef __attribute__((ext_vector_type(8))) short bf16x8;
typedef __attribute__((ext_vector_type(4))) float f32x4;

__device__ __forceinline__ void atomAddF(float* p, float v) { unsafeAtomicAdd(p, v); }

__device__ __forceinline__ unsigned short f2bf(float f) {  // RNE f32->bf16
  unsigned u = __builtin_bit_cast(unsigned, f);
  unsigned r = u + 0x7fffu + ((u >> 16) & 1u);
  return (unsigned short)(r >> 16);
}
__device__ __forceinline__ float bf2f(unsigned short h) {
  return __builtin_bit_cast(float, (unsigned)h << 16);
}
__device__ __forceinline__ float blo(unsigned u) { return __builtin_bit_cast(float, u << 16); }
__device__ __forceinline__ float bhi(unsigned u) { return __builtin_bit_cast(float, u & 0xffff0000u); }
__device__ __forceinline__ unsigned pk2(float a, float b) {
  return (unsigned)f2bf(a) | ((unsigned)f2bf(b) << 16);
}

// async global(16B) -> LDS DMA; dest = wave-uniform base + lane*16
__device__ __forceinline__ void gload16(const unsigned short* g, unsigned short* l) {
  __builtin_amdgcn_global_load_lds(
      (const __attribute__((address_space(1))) unsigned int*)g,
      (__attribute__((address_space(3))) unsigned int*)l, 16, 0, 0);
}

__device__ __forceinline__ void fma8(const uint4& q, float w, float* acc) {
  acc[0] = fmaf(blo(q.x), w, acc[0]);
  acc[1] = fmaf(bhi(q.x), w, acc[1]);
  acc[2] = fmaf(blo(q.y), w, acc[2]);
  acc[3] = fmaf(bhi(q.y), w, acc[3]);
  acc[4] = fmaf(blo(q.z), w, acc[4]);
  acc[5] = fmaf(bhi(q.z), w, acc[5]);
  acc[6] = fmaf(blo(q.w), w, acc[6]);
  acc[7] = fmaf(bhi(q.w), w, acc[7]);
}

// ---------------- merged prep + degree/count ----------------
// Blocks [0, edgeBlocks): ONE packed u64 atomic per edge:
//   cnt64[c] += (1 << 40) + round(w * 2^24)   (count in high bits, fixed-point
//   weight-sum in low bits; sum < 2^30 so no carry into the count field).
// Blocks [edgeBlocks, ..): conversions (st zero, W1T, W2T, xbf).
// cnt64 pre-zeroed by hipMemsetAsync; self-loop folded into rsqrt(sum+1) later.
__global__ void k_prep_deg(const float* __restrict__ x, unsigned short* __restrict__ xbf,
                           float* __restrict__ st,
                           const float* __restrict__ W1, unsigned short* __restrict__ W1T,
                           const float* __restrict__ W2, unsigned short* __restrict__ W2T,
                           unsigned long long* __restrict__ cnt64,
                           const int* __restrict__ ei, const float* __restrict__ ew,
                           int n, int nE, int edgeBlocks) {
  if ((int)blockIdx.x < edgeBlocks) {
    int i = blockIdx.x * blockDim.x + threadIdx.x;
    if (i < nE) {
      int c = ei[nE + i];
      unsigned long long v =
          (1ULL << 40) + (unsigned long long)__float2uint_rn(ew[i] * 16777216.0f);
      atomicAdd(&cnt64[c], v);
    }
    return;
  }
  int i = (blockIdx.x - edgeBlocks) * blockDim.x + threadIdx.x;
  if (i < 4096) st[i] = 0.f;
  if (i < kIn * kH1) {  // W1T[512][128]
    int nn = i / kIn, k = i - nn * kIn;
    W1T[i] = f2bf(W1[(size_t)k * kH1 + nn]);
  }
  if (i < kW2R * kH1) {  // W2T[384][512], rows >=300 zero
    int nn = i / kH1, k = i - nn * kH1;
    W2T[i] = (nn < kH2) ? f2bf(W2[(size_t)k * kH2 + nn]) : (unsigned short)0;
  }
  if (i < n * 16) {  // xbf row-major [n][128]
    int node = i >> 4, g = i & 15;
    const float4* xp = reinterpret_cast<const float4*>(x + (size_t)node * kIn + g * 8);
    float4 v0 = xp[0], v1 = xp[1];
    uint4 o;
    o.x = pk2(v0.x, v0.y); o.y = pk2(v0.z, v0.w);
    o.z = pk2(v1.x, v1.y); o.w = pk2(v1.z, v1.w);
    reinterpret_cast<uint4*>(xbf)[i] = o;
  }
}

// ---------------- 2-phase scan: unpack cnt64 -> (dis, local scan), block sums ----------------
__global__ void k_scan_a(const unsigned long long* __restrict__ cnt64, int* __restrict__ cnt,
                         int* __restrict__ bsum, float* __restrict__ dis, int n) {
  __shared__ int ws[4];
  int i = blockIdx.x * 256 + threadIdx.x;
  int lane = threadIdx.x & 63, wid = threadIdx.x >> 6;
  unsigned long long cv = (i < n) ? cnt64[i] : 0ULL;
  if (i < n)  // deg = fixed-point weight sum + 1 (self loop)
    dis[i] = rsqrtf(1.0f + (float)(unsigned)cv * (1.0f / 16777216.0f));
  int v = (int)(cv >> 40);
  int s = v;
#pragma unroll
  for (int off = 1; off < 64; off <<= 1) {
    int t = __shfl_up(s, off);
    if (lane >= off) s += t;
  }
  if (lane == 63) ws[wid] = s;
  __syncthreads();
  int add = 0;
  if (wid > 0) add += ws[0];
  if (wid > 1) add += ws[1];
  if (wid > 2) add += ws[2];
  if (i < n) cnt[i] = s - v + add;  // block-local exclusive scan
  if (threadIdx.x == 255) bsum[blockIdx.x] = add + s;
}

__global__ void k_scan_b(int* __restrict__ bsum, int nb) {  // nb <= 256, one block
  __shared__ int ws[4];
  int i = threadIdx.x;
  int lane = i & 63, wid = i >> 6;
  int v = (i < nb) ? bsum[i] : 0;
  int s = v;
#pragma unroll
  for (int off = 1; off < 64; off <<= 1) {
    int t = __shfl_up(s, off);
    if (lane >= off) s += t;
  }
  if (lane == 63) ws[wid] = s;
  __syncthreads();
  int add = 0;
  if (wid > 0) add += ws[0];
  if (wid > 1) add += ws[1];
  if (wid > 2) add += ws[2];
  if (i < nb) bsum[i] = s - v + add;  // exclusive block prefix
}

// scatter: global position = local scan + block prefix
__global__ void k_scatter(int* __restrict__ cnt, const int* __restrict__ bsum,
                          const int* __restrict__ ei, const float* __restrict__ w,
                          const float* __restrict__ dis, uint2* __restrict__ pr, int nE) {
  int i = blockIdx.x * blockDim.x + threadIdx.x;
  if (i < nE) {
    int r = ei[i];
    int c = ei[nE + i];
    int pos = atomicAdd(&cnt[c], 1) + bsum[c >> 8];
    float ww = dis[r] * w[i] * dis[c];
    pr[pos] = make_uint2((unsigned)r, __builtin_bit_cast(unsigned, ww));
  }
}

// ---------------- gather propagate: bf16 in/out, 16B granules, 4x unrolled ----------------
// endp holds block-local ends; true end = endp[v] + bsum[v>>8].
template<int NSQ>  // uint4 granules per row
__global__ void k_gather(const unsigned short* __restrict__ X, const int* __restrict__ endp,
                         const int* __restrict__ bsum, const uint2* __restrict__ pr,
                         const float* __restrict__ dis, unsigned short* __restrict__ out, int n) {
  int tid = blockIdx.x * blockDim.x + threadIdx.x;
  int v = tid / NSQ;
  int s = tid - v * NSQ;
  if (v >= n) return;
  int beg = (v == 0) ? 0 : endp[v - 1] + bsum[(v - 1) >> 8];
  int end = endp[v] + bsum[v >> 8];
  const uint4* Xr = reinterpret_cast<const uint4*>(X);
  float d = dis[v];
  float sw = d * d;
  float acc[8];
  {
    uint4 q = Xr[(size_t)v * NSQ + s];
    acc[0] = blo(q.x) * sw; acc[1] = bhi(q.x) * sw;
    acc[2] = blo(q.y) * sw; acc[3] = bhi(q.y) * sw;
    acc[4] = blo(q.z) * sw; acc[5] = bhi(q.z) * sw;
    acc[6] = blo(q.w) * sw; acc[7] = bhi(q.w) * sw;
  }
  int e = beg;
  for (; e + 4 <= end; e += 4) {
    uint2 p0 = pr[e], p1 = pr[e + 1], p2 = pr[e + 2], p3 = pr[e + 3];
    uint4 q0 = Xr[(size_t)p0.x * NSQ + s];
    uint4 q1 = Xr[(size_t)p1.x * NSQ + s];
    uint4 q2 = Xr[(size_t)p2.x * NSQ + s];
    uint4 q3 = Xr[(size_t)p3.x * NSQ + s];
    fma8(q0, __builtin_bit_cast(float, p0.y), acc);
    fma8(q1, __builtin_bit_cast(float, p1.y), acc);
    fma8(q2, __builtin_bit_cast(float, p2.y), acc);
    fma8(q3, __builtin_bit_cast(float, p3.y), acc);
  }
  for (; e < end; ++e) {
    uint2 p = pr[e];
    uint4 q = Xr[(size_t)p.x * NSQ + s];
    fma8(q, __builtin_bit_cast(float, p.y), acc);
  }
  uint4 o;
  o.x = pk2(acc[0], acc[1]);
  o.y = pk2(acc[2], acc[3]);
  o.z = pk2(acc[4], acc[5]);
  o.w = pk2(acc[6], acc[7]);
  reinterpret_cast<uint4*>(out)[(size_t)v * NSQ + s] = o;
}

// ---------------- bf16 MFMA GEMM (m97 structure) ----------------
// STATS: fused per-column BatchNorm sum / sum-of-squares on the f32 accumulators.
template<bool STATS>
__global__ __launch_bounds__(256) void k_gemm(const unsigned short* __restrict__ A,
    const unsigned short* __restrict__ BT, unsigned short* __restrict__ C,
    float* __restrict__ s1g, float* __restrict__ s2g,
    int M, int Nlog, int K, int ntiles, int nwg) {
  constexpr int BK = 64;
  __shared__ unsigned short lA[(BK / 8) * 128 * 8];  // 16 KB
  __shared__ unsigned short lB[(BK / 8) * 128 * 8];
  __shared__ float sS[128], sQ[128];

  int p = blockIdx.x;
  int xcd = p & 7, idx = p >> 3;
  int q8 = nwg >> 3, r8 = nwg & 7;
  int logical = (xcd < r8 ? xcd * (q8 + 1) : r8 * (q8 + 1) + (xcd - r8) * q8) + idx;
  const int nt = logical % ntiles;
  const int mt = logical / ntiles;
  const int m0 = mt * 128, n0 = nt * 128;

  const int tid = threadIdx.x, lane = tid & 63, wid = tid >> 6;
  const int wr = wid >> 1, wc = wid & 1;
  const int fr = lane & 15, fq = lane >> 4;

  if constexpr (STATS) {
    if (tid < 128) { sS[tid] = 0.f; sQ[tid] = 0.f; }  // covered by first K-loop barrier
  }

  int arow[4], brow[4], k8s[4];
#pragma unroll
  for (int j = 0; j < 4; ++j) {
    int g = tid + 256 * j;
    int row = g & 127;
    k8s[j] = g >> 7;
    int ar = m0 + row;
    arow[j] = (ar < M) ? ar : (M - 1);  // clamp: in-bounds, result discarded
    brow[j] = n0 + row;                 // BT padded: always valid
  }

  f32x4 acc[4][4] = {};

  for (int k0 = 0; k0 < K; k0 += BK) {
    __syncthreads();
#pragma unroll
    for (int j = 0; j < 4; ++j) {
      int g = tid + 256 * j;
      gload16(A  + (size_t)arow[j] * K + k0 + k8s[j] * 8, &lA[g * 8]);
      gload16(BT + (size_t)brow[j] * K + k0 + k8s[j] * 8, &lB[g * 8]);
    }
    __syncthreads();
#pragma unroll
    for (int step = 0; step < 2; ++step) {
      bf16x8 af[4], bf[4];
#pragma unroll
      for (int m = 0; m < 4; ++m)
        af[m] = *reinterpret_cast<const bf16x8*>(
            &lA[(((step * 4 + fq) << 7) + wr * 64 + m * 16 + fr) * 8]);
#pragma unroll
      for (int nn = 0; nn < 4; ++nn)
        bf[nn] = *reinterpret_cast<const bf16x8*>(
            &lB[(((step * 4 + fq) << 7) + wc * 64 + nn * 16 + fr) * 8]);
#pragma unroll
      for (int m = 0; m < 4; ++m)
#pragma unroll
        for (int nn = 0; nn < 4; ++nn)
          acc[m][nn] = __builtin_amdgcn_mfma_f32_16x16x32_bf16(af[m], bf[nn], acc[m][nn], 0, 0, 0);
    }
  }

#pragma unroll
  for (int m = 0; m < 4; ++m) {
#pragma unroll
    for (int r = 0; r < 4; ++r) {
      int row = m0 + wr * 64 + m * 16 + fq * 4 + r;
      if (row >= M) continue;
#pragma unroll
      for (int nn = 0; nn < 4; ++nn) {
        int col = n0 + wc * 64 + nn * 16 + fr;
        if (col < Nlog)
          C[(size_t)row * Nlog + col] = f2bf(acc[m][nn][r]);
      }
    }
  }

  if constexpr (STATS) {
    float ps[4] = {}, pq[4] = {};
#pragma unroll
    for (int m = 0; m < 4; ++m) {
#pragma unroll
      for (int r = 0; r < 4; ++r) {
        int row = m0 + wr * 64 + m * 16 + fq * 4 + r;
        if (row < M) {
#pragma unroll
          for (int nn = 0; nn < 4; ++nn) {
            float v = acc[m][nn][r];
            ps[nn] += v;
            pq[nn] = fmaf(v, v, pq[nn]);
          }
        }
      }
    }
#pragma unroll
    for (int nn = 0; nn < 4; ++nn) {
      int cl = wc * 64 + nn * 16 + fr;
      atomicAdd(&sS[cl], ps[nn]);  // LDS float atomic
      atomicAdd(&sQ[cl], pq[nn]);
    }
    __syncthreads();
    if (tid < 128) {
      atomAddF(&s1g[n0 + tid], sS[tid]);
      atomAddF(&s2g[n0 + tid], sQ[tid]);
    }
  }
}

// ---------------- coalesced BatchNorm stats (layer 2) ----------------
template<int C>
__global__ __launch_bounds__(256) void k_bn_stats_co(const unsigned short* __restrict__ H,
                                                     float* __restrict__ s1, float* __restrict__ s2,
                                                     int n, int rpb) {
  constexpr int G = C / 8;
  __shared__ float redS[3][G][8];
  __shared__ float redQ[3][G][8];
  const int g = threadIdx.x & 63;
  const int rr = threadIdx.x >> 6;
  int r0 = blockIdx.x * rpb;
  int r1 = r0 + rpb; if (r1 > n) r1 = n;
  float sa[8] = {}, sq[8] = {};
  if (g < G) {
    for (int r = r0 + rr; r < r1; r += 4) {
      uint4 q = *reinterpret_cast<const uint4*>(H + (size_t)r * C + g * 8);
      float v[8] = {blo(q.x), bhi(q.x), blo(q.y), bhi(q.y),
                    blo(q.z), bhi(q.z), blo(q.w), bhi(q.w)};
#pragma unroll
      for (int j = 0; j < 8; ++j) {
        sa[j] += v[j];
        sq[j] = fmaf(v[j], v[j], sq[j]);
      }
    }
    if (rr > 0) {
#pragma unroll
      for (int j = 0; j < 8; ++j) {
        redS[rr - 1][g][j] = sa[j];
        redQ[rr - 1][g][j] = sq[j];
      }
    }
  }
  __syncthreads();
  if (rr == 0 && g < G) {
#pragma unroll
    for (int j = 0; j < 8; ++j) {
      float ts = sa[j] + redS[0][g][j] + redS[1][g][j] + redS[2][g][j];
      float tq = sq[j] + redQ[0][g][j] + redQ[1][g][j] + redQ[2][g][j];
      atomAddF(&s1[g * 8 + j], ts);
      atomAddF(&s2[g * 8 + j], tq);
    }
  }
}

// in-place BN+ReLU on bf16 buffer with fused finalize (reads raw stats). C power of 2.
template<int C>
__global__ void k_bn_apply_relu_bf16(unsigned short* __restrict__ H,
                                     const float* __restrict__ s1, const float* __restrict__ s2,
                                     const float* __restrict__ g, const float* __restrict__ be,
                                     float invN, int total8) {
  int i = blockIdx.x * blockDim.x + threadIdx.x;
  if (i >= total8) return;
  int c = (i * 8) & (C - 1);
  float sc[8], sh[8];
#pragma unroll
  for (int j = 0; j < 8; ++j) {  // inline bn_finalize (L2-hot 2KB arrays)
    float mean = s1[c + j] * invN;
    float var = fmaxf(s2[c + j] * invN - mean * mean, 0.f);
    float s = g[c + j] * rsqrtf(var + kEps);
    sc[j] = s;
    sh[j] = be[c + j] - mean * s;
  }
  uint4 q = reinterpret_cast<uint4*>(H)[i];
  unsigned w[4] = {q.x, q.y, q.z, q.w};
  unsigned o[4];
#pragma unroll
  for (int j = 0; j < 4; ++j) {
    float lo = fmaxf(fmaf(blo(w[j]), sc[j * 2],     sh[j * 2]),     0.f);
    float hi = fmaxf(fmaf(bhi(w[j]), sc[j * 2 + 1], sh[j * 2 + 1]), 0.f);
    o[j] = pk2(lo, hi);
  }
  reinterpret_cast<uint4*>(H)[i] = make_uint4(o[0], o[1], o[2], o[3]);
}

// ---------------- head: BN2-finalize + apply + relu + @Wl + bl + relu + log_softmax ----------------
__global__ __launch_bounds__(256) void k_head(const unsigned short* __restrict__ H,
    const float* __restrict__ s1, const float* __restrict__ s2,
    const float* __restrict__ g2, const float* __restrict__ be2,
    const float* __restrict__ Wl, const float* __restrict__ bl,
    float* __restrict__ out, int n, float invN) {
  __shared__ float sW[kH2 * kOut];
  __shared__ float sScale[kH2], sShift[kH2];
  for (int i = threadIdx.x; i < kH2 * kOut; i += blockDim.x) sW[i] = Wl[i];
  for (int i = threadIdx.x; i < kH2; i += blockDim.x) {  // fused bn_finalize2
    float mean = s1[i] * invN;
    float var = fmaxf(s2[i] * invN - mean * mean, 0.f);
    float sc = g2[i] * rsqrtf(var + kEps);
    sScale[i] = sc;
    sShift[i] = be2[i] - mean * sc;
  }
  __syncthreads();
  float blv[kOut];
#pragma unroll
  for (int j = 0; j < kOut; ++j) blv[j] = bl[j];
  const int lane = threadIdx.x & 63;
  const int wid = (blockIdx.x * blockDim.x + threadIdx.x) >> 6;
  const int nw  = (gridDim.x * blockDim.x) >> 6;
  for (int node = wid; node < n; node += nw) {
    const unsigned short* hrow = H + (size_t)node * kH2p;
    float acc[kOut] = {};
    for (int k = lane; k < kH2; k += 64) {
      float v = fmaxf(fmaf(bf2f(hrow[k]), sScale[k], sShift[k]), 0.f);
      const float* wr = sW + k * kOut;
#pragma unroll
      for (int j = 0; j < kOut; ++j) acc[j] = fmaf(v, wr[j], acc[j]);
    }
#pragma unroll
    for (int j = 0; j < kOut; ++j) {
      float v = acc[j];
      for (int off = 32; off > 0; off >>= 1) v += __shfl_down(v, off);
      acc[j] = v;
    }
    if (lane == 0) {
      float vv[kOut], m = -1e30f;
#pragma unroll
      for (int j = 0; j < kOut; ++j) {
        vv[j] = fmaxf(acc[j] + blv[j], 0.f);
        m = fmaxf(m, vv[j]);
      }
      float s = 0.f;
#pragma unroll
      for (int j = 0; j < kOut; ++j) s += expf(vv[j] - m);
      float lse = m + logf(s);
      float* o = out + (size_t)node * kOut;
#pragma unroll
      for (int j = 0; j < kOut; ++j) o[j] = vv[j] - lse;
    }
  }
}

}  // namespace

extern "C" void kernel_launch(void* const* d_in, const int* in_sizes, int n_in,
                              void* d_out, int out_size, void* d_ws, size_t ws_size,
                              hipStream_t stream) {
  const float* x   = (const float*)d_in[0];
  const int*   ei  = (const int*)d_in[1];
  const float* ew  = (const float*)d_in[2];
  const float* W1  = (const float*)d_in[3];
  // d_in[4] = b1: constant per column -> cancelled by BN1 mean subtraction
  const float* g1  = (const float*)d_in[5];
  const float* be1 = (const float*)d_in[6];
  const float* W2  = (const float*)d_in[7];
  // d_in[8] = b2: cancelled by BN2
  const float* g2  = (const float*)d_in[9];
  const float* be2 = (const float*)d_in[10];
  const float* Wl  = (const float*)d_in[11];
  const float* bl  = (const float*)d_in[12];
  float* out = (float*)d_out;
  float* ws  = (float*)d_ws;

  const int n = in_sizes[0] / kIn;  // 50000
  const int e = in_sizes[1] / 2;    // 800000

  // workspace (float units), ~145 MB:
  float* dis = ws;                                          // 50048
  int*   cnt = (int*)(ws + 50048);                          // 50048
  unsigned long long* cnt64 = (unsigned long long*)(ws + 100096);  // 50048 u64 = 100096 fl
  uint2* pr  = (uint2*)(ws + 200192);                       // 800000 pairs = 1.6M fl
  float* st  = ws + 1800192;                                // 4096
  float* s1a = st,        *s2a = st + 512;
  float* s1b = st + 2048, *s2b = st + 2560;
  int*   bsum = (int*)(ws + 1804288);                       // 512
  unsigned short* xbf = (unsigned short*)(ws + 1804800);    // [n][128] = 3.2M fl
  unsigned short* W1T = (unsigned short*)(ws + 5004800);    // 512x128 = 32768 fl
  unsigned short* W2T = (unsigned short*)(ws + 5037568);    // 384x512 = 98304 fl
  unsigned short* agg1 = (unsigned short*)(ws + 5135872);   // [n][128] = 3.2M fl
  unsigned short* h1   = (unsigned short*)(ws + 8335872);   // [n][512] = 12.8M fl
  unsigned short* t2   = (unsigned short*)(ws + 21135872);  // [n][304] = 7.6M fl
  unsigned short* agg2 = (unsigned short*)(ws + 28735872);  // [n][304] = 7.6M fl

  constexpr int TPB = 256;
  const int nb = (n + 255) / 256;   // scan blocks (196 <= 256)
  const int rpb = (n + 255) / 256;  // stats rows per block

  // ---- init cnt64 + merged prep/deg + CSC build ----
  hipMemsetAsync(cnt64, 0, (size_t)50048 * sizeof(unsigned long long), stream);
  {
    int edgeBlocks = (e + TPB - 1) / TPB;          // 3125
    int convBlocks = (n * 16 + TPB - 1) / TPB;     // 3125
    k_prep_deg<<<edgeBlocks + convBlocks, TPB, 0, stream>>>(
        x, xbf, st, W1, W1T, W2, W2T, cnt64, ei, ew, n, e, edgeBlocks);
  }
  k_scan_a<<<nb, 256, 0, stream>>>(cnt64, cnt, bsum, dis, n);
  k_scan_b<<<1, 256, 0, stream>>>(bsum, nb);
  k_scatter<<<(e + TPB - 1) / TPB, TPB, 0, stream>>>(cnt, bsum, ei, ew, dis, pr, e);

  const int mtiles = (n + 127) / 128;  // 391

  // ---- layer 1: agg1 = A(xbf); h1 = bf16(agg1@W1) + fused BN1 stats; BN+ReLU in place ----
  {
    int tot = n * (kIn / 8);
    k_gather<kIn / 8><<<(tot + TPB - 1) / TPB, TPB, 0, stream>>>(xbf, cnt, bsum, pr, dis, agg1, n);
  }
  {
    int ntiles = kH1 / 128;            // 4
    int nwg = mtiles * ntiles;
    k_gemm<true><<<nwg, 256, 0, stream>>>(agg1, W1T, h1, s1a, s2a, n, kH1, kIn, ntiles, nwg);
  }
  k_bn_apply_relu_bf16<kH1><<<((n * (kH1 / 8)) + TPB - 1) / TPB, TPB, 0, stream>>>(
      h1, s1a, s2a, g1, be1, 1.0f / n, n * (kH1 / 8));

  // ---- layer 2: t2 = bf16(h1@W2); agg2 = A(t2); BN2 stats ----
  {
    int ntiles = kW2R / 128;           // 3
    int nwg = mtiles * ntiles;
    k_gemm<false><<<nwg, 256, 0, stream>>>(h1, W2T, t2, nullptr, nullptr, n, kH2p, kH1, ntiles, nwg);
  }
  {
    int tot = n * (kH2p / 8);
    k_gather<kH2p / 8><<<(tot + TPB - 1) / TPB, TPB, 0, stream>>>(t2, cnt, bsum, pr, dis, agg2, n);
  }
  k_bn_stats_co<kH2p><<<256, 256, 0, stream>>>(agg2, s1b, s2b, n, rpb);

  // ---- head (fused BN2 finalize) ----
  k_head<<<1024, 256, 0, stream>>>(agg2, s1b, s2b, g2, be2, Wl, bl, out, n, 1.0f / n);
}